// Round 18
// baseline (97.121 us; speedup 1.0000x reference)
//
#include <hip/hip_runtime.h>

#define TOK 16384
#define DD 1024
#define OO 1024
#define KE 1088     // 1024 + 16 lora cols + 48 zero pad (17 K-tiles of 64)
#define NT 17       // K-tiles in main GEMM
#define NB1 288     // B1 rows: 256 proj + 15 down + 17 zero pad
#define CLAMPV 4.605170185988091f

typedef __attribute__((ext_vector_type(8))) short short8;
typedef __attribute__((ext_vector_type(4))) float f32x4;
typedef __attribute__((ext_vector_type(2))) unsigned int uint2e;
typedef __attribute__((ext_vector_type(4))) unsigned int uint4e;

__device__ __forceinline__ unsigned short f2bf(float f) {
  unsigned int u = __float_as_uint(f);
  return (unsigned short)((u + 0x7FFFu + ((u >> 16) & 1u)) >> 16);
}

__device__ __forceinline__ void gload16(const unsigned short* g, unsigned short* l) {
  __builtin_amdgcn_global_load_lds(
      (const __attribute__((address_space(1))) void*)g,
      (__attribute__((address_space(3))) void*)l, 16, 0, 0);
}

__device__ __forceinline__ float down_val(int j, int d,
    const float* __restrict__ Wd0, const float* __restrict__ Wd1,
    const float* __restrict__ Wd2, const float* __restrict__ Wd3) {
  if (j == 0) return Wd0[d];
  if (j < 3) return Wd1[(j - 1) * DD + d];
  if (j < 7) return Wd2[(j - 3) * DD + d];
  if (j < 15) return Wd3[(j - 7) * DD + d];
  return 0.f;
}

// ---------------- kernel 0: prep (Bx bf16, B1L swizzle-blocked bf16, Ax pad, v4, c4) ----------------
// B1L layout: [16 K-tiles][288 rows][64 k] with k pre-XOR-swizzled: element (r, kt*64+k)
// stored at kk = k ^ ((r&7)<<3). Linear global_load_lds then yields T2-swizzled LDS.
__global__ __launch_bounds__(256) void prep3(
    const float* __restrict__ W, const float* __restrict__ Wp,
    const float* __restrict__ sim, const float* __restrict__ bp,
    const float* __restrict__ Wd0, const float* __restrict__ Wd1,
    const float* __restrict__ Wd2, const float* __restrict__ Wd3,
    const float* __restrict__ Wu0, const float* __restrict__ Wu1,
    const float* __restrict__ Wu2, const float* __restrict__ Wu3,
    unsigned short* __restrict__ Bx, unsigned short* __restrict__ B1,
    unsigned short* __restrict__ Ax, float* __restrict__ v4,
    float* __restrict__ c4) {
  __shared__ float simn_l[256][4];
  __shared__ float part[4][4];
  const int tid = threadIdx.x;
  if (blockIdx.x < 4) {
    float4 sv = *(const float4*)&sim[tid * 4];
    float v[4] = {sv.x * sv.x, sv.y * sv.y, sv.z * sv.z, sv.w * sv.w};
#pragma unroll
    for (int off = 1; off < 64; off <<= 1) {
#pragma unroll
      for (int e = 0; e < 4; ++e) v[e] += __shfl_xor(v[e], off, 64);
    }
    int wv = tid >> 6, ln = tid & 63;
    if (ln == 0) { part[wv][0] = v[0]; part[wv][1] = v[1]; part[wv][2] = v[2]; part[wv][3] = v[3]; }
    __syncthreads();
    float n0 = fmaxf(sqrtf(part[0][0] + part[1][0] + part[2][0] + part[3][0]), 1e-12f);
    float n1 = fmaxf(sqrtf(part[0][1] + part[1][1] + part[2][1] + part[3][1]), 1e-12f);
    float n2 = fmaxf(sqrtf(part[0][2] + part[1][2] + part[2][2] + part[3][2]), 1e-12f);
    float n3 = fmaxf(sqrtf(part[0][3] + part[1][3] + part[2][3] + part[3][3]), 1e-12f);
    simn_l[tid][0] = sv.x / n0; simn_l[tid][1] = sv.y / n1;
    simn_l[tid][2] = sv.z / n2; simn_l[tid][3] = sv.w / n3;
    __syncthreads();
    int d = blockIdx.x * 256 + tid;
    float a0 = 0.f, a1 = 0.f, a2 = 0.f, a3 = 0.f;
    for (int j = 0; j < 256; ++j) {
      float w = Wp[j * DD + d];
      a0 = __builtin_fmaf(w, simn_l[j][0], a0);
      a1 = __builtin_fmaf(w, simn_l[j][1], a1);
      a2 = __builtin_fmaf(w, simn_l[j][2], a2);
      a3 = __builtin_fmaf(w, simn_l[j][3], a3);
    }
    v4[d] = a0; v4[1024 + d] = a1; v4[2048 + d] = a2; v4[3072 + d] = a3;
    if (blockIdx.x == 0) {
      float bpv = bp[tid];
      float pc[4] = {simn_l[tid][0] * bpv, simn_l[tid][1] * bpv,
                     simn_l[tid][2] * bpv, simn_l[tid][3] * bpv};
#pragma unroll
      for (int off = 1; off < 64; off <<= 1) {
#pragma unroll
        for (int e = 0; e < 4; ++e) pc[e] += __shfl_xor(pc[e], off, 64);
      }
      __syncthreads();
      if (ln == 0) { part[wv][0] = pc[0]; part[wv][1] = pc[1]; part[wv][2] = pc[2]; part[wv][3] = pc[3]; }
      __syncthreads();
      if (tid == 0) {
#pragma unroll
        for (int e = 0; e < 4; ++e)
          c4[e] = part[0][e] + part[1][e] + part[2][e] + part[3][e];
      }
    }
  }
  const int nB1 = 16 * NB1 * 64;    // 294912 (swizzle-blocked)
  const int nWb = OO * KE;          // 1114112
  const int nXpad = TOK * 48;       // 786432 (cols 1040..1087)
  const int total = nB1 + nWb + nXpad;
  for (int i = blockIdx.x * 256 + tid; i < total; i += gridDim.x * 256) {
    if (i < nB1) {
      int kt = i / (NB1 * 64);
      int rem = i - kt * (NB1 * 64);
      int r = rem >> 6, kk = rem & 63;
      int k = kt * 64 + (kk ^ ((r & 7) << 3));
      float v = 0.f;
      if (r < 256) v = Wp[r * DD + k];
      else if (r < 271) v = down_val(r - 256, k, Wd0, Wd1, Wd2, Wd3);
      B1[i] = f2bf(v);
    } else if (i < nB1 + nWb) {
      int j = i - nB1;
      int o = j / KE, c = j - o * KE;
      float v = 0.f;
      if (c < 1024) v = W[o * DD + c];
      else if (c == 1024) v = Wu0[o];
      else if (c < 1027) v = Wu1[o * 2 + (c - 1025)];
      else if (c < 1031) v = Wu2[o * 4 + (c - 1027)];
      else if (c < 1039) v = Wu3[o * 8 + (c - 1031)];
      Bx[j] = f2bf(v);
    } else {
      int j = i - nB1 - nWb;
      int row = j / 48, c = j - row * 48;
      Ax[row * KE + 1040 + c] = 0;
    }
  }
}

// ---------------- kernel 1: gemm4f — K-outer, 2 row-tiles per block, B1-amortized ----------------
// 64 rows/block (2 subtiles of 32), 256 thr (4 waves 2m x 2n), grid 256 -> 1 block/CU.
// Per K-step: one B1 staging serves both subtiles; each B-fragment ds_read feeds 2 MFMAs.
// LDS 88 KB: bs1 2x36KB + as1 2x2x4KB.
__global__ __launch_bounds__(256, 1) void gemm4f(
    const float* __restrict__ x, const float* __restrict__ v4,
    unsigned short* __restrict__ Ax, const unsigned short* __restrict__ B1L,
    const float* __restrict__ c4, const float* __restrict__ bp,
    const float* __restrict__ temp) {
  __shared__ __align__(16) unsigned short as1[2][2][32 * 64];  // [dbuf][rt] 16 KB
  __shared__ __align__(16) unsigned short bs1[2][NB1 * 64];    // 72 KB
  const int tid = threadIdx.x;
  const int lane = tid & 63, wv = tid >> 6;    // 4 waves
  const int wm = wv >> 1, wn = wv & 1;         // 2m x 2n (wn: 144 cols each)
  const int r0 = blockIdx.x * 64;
  const int ro = lane & 15;
  const int rswz = (ro & 7) << 3;              // read-side k-swizzle (ushort units)
  const int xr = tid >> 3;                     // x staging: row 0..31 within subtile
  const int xc = (tid & 7) * 4;                // x staging: col quad within 32-col half
  const int aswz = (xr & 7) << 3;              // A write-side swizzle
  const float* xgp = &x[(r0 + xr) * DD + xc];
  unsigned short* axp = &Ax[(r0 + xr) * KE + xc];
  f32x4 acc[2][9] = {};
  float dotp[2][4] = {};

// 36 chunks of 8 rows x 64 k (1 KB); 36/4 waves = 9 gloads/thread, wave-uniform dest
#define STB1(KT, BUF)                                                         \
  for (int c = wv; c < 36; c += 4)                                            \
    gload16(&B1L[(KT) * (NB1 * 64) + c * 512 + lane * 8], &bs1[BUF][c * 512]);

#define XSTG(KT, RT, BUF)                                                     \
  _Pragma("unroll")                                                           \
  for (int h = 0; h < 2; ++h) {                                               \
    float4 xv = *(const float4*)(xgp + (RT) * 32 * DD + (KT) * 64 + h * 32);  \
    float4 va = *(const float4*)&v4[(KT) * 64 + h * 32 + xc];                 \
    float4 vb = *(const float4*)&v4[1024 + (KT) * 64 + h * 32 + xc];          \
    float4 vc = *(const float4*)&v4[2048 + (KT) * 64 + h * 32 + xc];          \
    float4 vd = *(const float4*)&v4[3072 + (KT) * 64 + h * 32 + xc];          \
    dotp[RT][0] = __builtin_fmaf(xv.x, va.x, __builtin_fmaf(xv.y, va.y,       \
        __builtin_fmaf(xv.z, va.z, __builtin_fmaf(xv.w, va.w, dotp[RT][0])))); \
    dotp[RT][1] = __builtin_fmaf(xv.x, vb.x, __builtin_fmaf(xv.y, vb.y,       \
        __builtin_fmaf(xv.z, vb.z, __builtin_fmaf(xv.w, vb.w, dotp[RT][1])))); \
    dotp[RT][2] = __builtin_fmaf(xv.x, vc.x, __builtin_fmaf(xv.y, vc.y,       \
        __builtin_fmaf(xv.z, vc.z, __builtin_fmaf(xv.w, vc.w, dotp[RT][2])))); \
    dotp[RT][3] = __builtin_fmaf(xv.x, vd.x, __builtin_fmaf(xv.y, vd.y,       \
        __builtin_fmaf(xv.z, vd.z, __builtin_fmaf(xv.w, vd.w, dotp[RT][3])))); \
    union { unsigned short s[4]; uint2e q; } pk;                              \
    pk.s[0] = f2bf(xv.x); pk.s[1] = f2bf(xv.y);                               \
    pk.s[2] = f2bf(xv.z); pk.s[3] = f2bf(xv.w);                               \
    *reinterpret_cast<uint2e*>(axp + (RT) * 32 * KE + (KT) * 64 + h * 32) = pk.q; \
    *reinterpret_cast<uint2e*>(                                               \
        &as1[BUF][RT][xr * 64 + (((h << 5) + xc) ^ aswz)]) = pk.q;            \
  }

// both row-tiles per B-fragment read (bf reused across rt)
#define MM2(BUF)                                                              \
  _Pragma("unroll")                                                           \
  for (int kh = 0; kh < 2; ++kh) {                                            \
    const int kb = ((kh << 5) + ((lane >> 4) << 3)) ^ rswz;                   \
    short8 af0 = *reinterpret_cast<const short8*>(                            \
        &as1[BUF][0][(wm * 16 + ro) * 64 + kb]);                              \
    short8 af1 = *reinterpret_cast<const short8*>(                            \
        &as1[BUF][1][(wm * 16 + ro) * 64 + kb]);                              \
    _Pragma("unroll")                                                         \
    for (int n = 0; n < 9; ++n) {                                             \
      short8 bf = *reinterpret_cast<const short8*>(                           \
          &bs1[BUF][(wn * 144 + n * 16 + ro) * 64 + kb]);                     \
      acc[0][n] = __builtin_amdgcn_mfma_f32_16x16x32_bf16(af0, bf, acc[0][n], 0, 0, 0); \
      acc[1][n] = __builtin_amdgcn_mfma_f32_16x16x32_bf16(af1, bf, acc[1][n], 0, 0, 0); \
    }                                                                         \
  }

  // ---- prologue ----
  STB1(0, 0)
  XSTG(0, 0, 0)
  XSTG(0, 1, 0)
  __syncthreads();
  int cur = 0;
  for (int u = 0; u < 16; ++u) {
    if (u < 15) {
      STB1(u + 1, cur ^ 1)
      XSTG(u + 1, 0, cur ^ 1)
      XSTG(u + 1, 1, cur ^ 1)
    }
    MM2(cur)
    if (u < 15) {
      __syncthreads();
      cur ^= 1;
    }
  }
  __syncthreads();

  // ---- epilogue scratch overlaid on bs1[0] (last MM2 read bs1[1]) ----
  float* eps = (float*)&bs1[0][0];
  float* ssq_s = eps;             // [2][64]  (wn-half x row)
  float* xdown_s = eps + 128;     // [64][16]
  float* dots_s = eps + 1152;     // [64][4]

  // fp32 dots: reduce over the 8 lanes sharing a row (lane bits 0..2)
#pragma unroll
  for (int off = 1; off < 8; off <<= 1) {
#pragma unroll
    for (int rt = 0; rt < 2; ++rt)
#pragma unroll
      for (int e = 0; e < 4; ++e) dotp[rt][e] += __shfl_xor(dotp[rt][e], off, 64);
  }
  if ((lane & 7) == 0) {
#pragma unroll
    for (int rt = 0; rt < 2; ++rt) {
      dots_s[(rt * 32 + xr) * 4 + 0] = dotp[rt][0];
      dots_s[(rt * 32 + xr) * 4 + 1] = dotp[rt][1];
      dots_s[(rt * 32 + xr) * 4 + 2] = dotp[rt][2];
      dots_s[(rt * 32 + xr) * 4 + 3] = dotp[rt][3];
    }
  }

  // per-thread ssq over proj cols (col < 256), bias added
  float ssqp[2][4] = {};
#pragma unroll
  for (int n = 0; n < 9; ++n) {
    int col = wn * 144 + n * 16 + ro;
    if (col < 256) {
      float b = bp[col];
#pragma unroll
      for (int rt = 0; rt < 2; ++rt)
#pragma unroll
        for (int r = 0; r < 4; ++r) {
          float a = acc[rt][n][r] + b;
          ssqp[rt][r] = __builtin_fmaf(a, a, ssqp[rt][r]);
        }
    }
  }
#pragma unroll
  for (int off = 1; off < 16; off <<= 1) {
#pragma unroll
    for (int rt = 0; rt < 2; ++rt)
#pragma unroll
      for (int r = 0; r < 4; ++r) ssqp[rt][r] += __shfl_xor(ssqp[rt][r], off, 64);
  }
  if (ro == 0) {
#pragma unroll
    for (int rt = 0; rt < 2; ++rt)
#pragma unroll
      for (int r = 0; r < 4; ++r)
        ssq_s[wn * 64 + rt * 32 + wm * 16 + (lane >> 4) * 4 + r] = ssqp[rt][r];
  }
  // xdown cols 256..270: wn=1, frag n=7, ro<15
  if (wn == 1 && ro < 15) {
#pragma unroll
    for (int rt = 0; rt < 2; ++rt)
#pragma unroll
      for (int r = 0; r < 4; ++r)
        xdown_s[(rt * 32 + wm * 16 + (lane >> 4) * 4 + r) * 16 + ro] = acc[rt][7][r];
  }
  __syncthreads();

  if (tid < 64) {
    const int row = tid, t = r0 + row;
    float ssqT = ssq_s[row] + ssq_s[64 + row];
    float4 cc = *reinterpret_cast<const float4*>(c4);
    float scale = expf(fminf(temp[0], CLAMPV));
    float inv = scale / fmaxf(sqrtf(ssqT), 1e-12f);
    float l[4];
    l[0] = (dots_s[row * 4 + 0] + cc.x) * inv; l[1] = (dots_s[row * 4 + 1] + cc.y) * inv;
    l[2] = (dots_s[row * 4 + 2] + cc.z) * inv; l[3] = (dots_s[row * 4 + 3] + cc.w) * inv;
    int be = 0; float m = l[0];
    if (l[1] > m) { m = l[1]; be = 1; }
    if (l[2] > m) { m = l[2]; be = 2; }
    if (l[3] > m) { m = l[3]; be = 3; }
    float den = expf(l[0] - m) + expf(l[1] - m) + expf(l[2] - m) + expf(l[3] - m);
    float g = 1.0f / den;
    int off = (1 << be) - 1;   // {0,1,3,7}
    int rr = 1 << be;          // {1,2,4,8}
    union { unsigned short s[16]; uint4e v[2]; } o;
#pragma unroll
    for (int j = 0; j < 16; ++j) {
      float dv = xdown_s[row * 16 + (j & 15)];
      float v = (j >= off && j < off + rr) ? g * dv : 0.f;
      o.s[j] = f2bf(v);
    }
    uint4e* dst = reinterpret_cast<uint4e*>(&Ax[t * KE + 1024]);
    dst[0] = o.v[0];
    dst[1] = o.v[1];
  }
#undef STB1
#undef XSTG
#undef MM2
}

// ---------------- kernel 2: main_gemm8 — 256x256 8-phase bf16 MFMA GEMM (plain C stores) ----------
__global__ __launch_bounds__(512, 2) void main_gemm8(
    const unsigned short* __restrict__ A, const unsigned short* __restrict__ Bm,
    float* __restrict__ C) {
  __shared__ __align__(16) unsigned short lbuf[2][32768];
  const int tid = threadIdx.x;
  const int lane = tid & 63, wv = tid >> 6;
  const int wm = wv >> 2, wn = wv & 3;
  const int dd = blockIdx.x;
  const int tt = (dd & 7) * 32 + (dd >> 3);
  const int bx = tt & 3, by = tt >> 2;
  const int r0 = by * 256, c0 = bx * 256;
  const int ro = lane & 15, ko = (lane >> 4) * 8;
  const int rowb = ro * 128;
  const int swz = (ro & 7) << 4;
  const int lk0 = (ko * 2) ^ swz;
  const int lk1 = (64 + ko * 2) ^ swz;
  const int ll = (lane * 16) ^ ((lane >> 3) << 4);
  const int sro = ll >> 7;
  const int sk = (ll & 127) >> 1;
  f32x4 acc[8][4] = {};
  short8 Af[4][2], B0[2][2], B1r[2][2];

#define STG(MTX, GRB, HBU, BUF, U2)                                           \
  do {                                                                        \
    gload16(&MTX[((GRB) + (0 * 8 + wv) * 8 + sro) * KE + (U2) * 64 + sk],     \
            &lbuf[BUF][(HBU) + (0 * 8 + wv) * 512]);                          \
    gload16(&MTX[((GRB) + (1 * 8 + wv) * 8 + sro) * KE + (U2) * 64 + sk],     \
            &lbuf[BUF][(HBU) + (1 * 8 + wv) * 512]);                          \
  } while (0)

#define LDA(FI, QM, LK) (*reinterpret_cast<const short8*>(                    \
    (const char*)Ab + wm * 16384 + (QM) * 8192 + (FI) * 2048 + rowb + (LK)))
#define LDB(FN, QN, LK) (*reinterpret_cast<const short8*>(                    \
    (const char*)Bb + wn * 8192 + (QN) * 4096 + (FN) * 2048 + rowb + (LK)))

#define MMQ(QM, QN, BF)                                                       \
  do {                                                                        \
    _Pragma("unroll")                                                         \
    for (int fi = 0; fi < 4; ++fi) {                                          \
      _Pragma("unroll")                                                       \
      for (int fn = 0; fn < 2; ++fn) {                                        \
        acc[(QM)*4+fi][(QN)*2+fn] = __builtin_amdgcn_mfma_f32_16x16x32_bf16(  \
            Af[fi][0], BF[fn][0], acc[(QM)*4+fi][(QN)*2+fn], 0, 0, 0);        \
        acc[(QM)*4+fi][(QN)*2+fn] = __builtin_amdgcn_mfma_f32_16x16x32_bf16(  \
            Af[fi][1], BF[fn][1], acc[(QM)*4+fi][(QN)*2+fn], 0, 0, 0);        \
      }                                                                       \
    }                                                                         \
  } while (0)

  STG(Bm, c0,       16384, 0, 0);
  STG(A,  r0,       0,     0, 0);
  STG(Bm, c0 + 128, 24576, 0, 0);
  STG(A,  r0 + 128, 8192,  0, 0);
  STG(Bm, c0,       16384, 1, 1);
  STG(A,  r0,       0,     1, 1);
  asm volatile("s_waitcnt vmcnt(4)" ::: "memory");
  __builtin_amdgcn_s_barrier();

  for (int u = 0; u < NT; ++u) {
    const int db = u & 1;
    const unsigned short* Ab = &lbuf[db][0];
    const unsigned short* Bb = &lbuf[db][16384];
#pragma unroll
    for (int fi = 0; fi < 4; ++fi) { Af[fi][0] = LDA(fi, 0, lk0); Af[fi][1] = LDA(fi, 0, lk1); }
#pragma unroll
    for (int fn = 0; fn < 2; ++fn) { B0[fn][0] = LDB(fn, 0, lk0); B0[fn][1] = LDB(fn, 0, lk1); }
    if (u + 1 < NT) STG(Bm, c0 + 128, 24576, (u + 1) & 1, u + 1);
    __builtin_amdgcn_s_barrier();
    __builtin_amdgcn_s_setprio(1);
    MMQ(0, 0, B0);
    __builtin_amdgcn_s_setprio(0);
    __builtin_amdgcn_s_barrier();
#pragma unroll
    for (int fn = 0; fn < 2; ++fn) { B1r[fn][0] = LDB(fn, 1, lk0); B1r[fn][1] = LDB(fn, 1, lk1); }
    if (u + 1 < NT) STG(A, r0 + 128, 8192, (u + 1) & 1, u + 1);
    __builtin_amdgcn_s_barrier();
    __builtin_amdgcn_s_setprio(1);
    MMQ(0, 1, B1r);
    __builtin_amdgcn_s_setprio(0);
    __builtin_amdgcn_s_barrier();
#pragma unroll
    for (int fi = 0; fi < 4; ++fi) { Af[fi][0] = LDA(fi, 1, lk0); Af[fi][1] = LDA(fi, 1, lk1); }
    if (u + 2 < NT) STG(Bm, c0, 16384, db, u + 2);
    __builtin_amdgcn_s_barrier();
    __builtin_amdgcn_s_setprio(1);
    MMQ(1, 1, B1r);
    __builtin_amdgcn_s_setprio(0);
    __builtin_amdgcn_s_barrier();
    if (u + 2 < NT) STG(A, r0, 0, db, u + 2);
    __builtin_amdgcn_s_barrier();
    __builtin_amdgcn_s_setprio(1);
    MMQ(1, 0, B0);
    __builtin_amdgcn_s_setprio(0);
    if (u + 2 < NT) {
      asm volatile("s_waitcnt vmcnt(4)" ::: "memory");
    } else if (u == NT - 2) {
      asm volatile("s_waitcnt vmcnt(0)" ::: "memory");
    }
    __builtin_amdgcn_s_barrier();
  }

#pragma unroll
  for (int m = 0; m < 8; ++m) {
    int rr = r0 + wm * 128 + m * 16 + (lane >> 4) * 4;
#pragma unroll
    for (int n = 0; n < 4; ++n) {
      int cc = c0 + wn * 64 + n * 16 + ro;
#pragma unroll
      for (int v = 0; v < 4; ++v)
        C[(rr + v) * OO + cc] = acc[m][n][v];
    }
  }
#undef STG
#undef LDA
#undef LDB
#undef MMQ
}

extern "C" void kernel_launch(void* const* d_in, const int* in_sizes, int n_in,
                              void* d_out, int out_size, void* d_ws, size_t ws_size,
                              hipStream_t stream) {
  const float* x    = (const float*)d_in[0];
  const float* W    = (const float*)d_in[1];
  const float* Wp   = (const float*)d_in[2];
  const float* bp   = (const float*)d_in[3];
  const float* sim  = (const float*)d_in[4];
  const float* temp = (const float*)d_in[5];
  const float* Wd0  = (const float*)d_in[6];
  const float* Wu0  = (const float*)d_in[7];
  const float* Wd1  = (const float*)d_in[8];
  const float* Wu1  = (const float*)d_in[9];
  const float* Wd2  = (const float*)d_in[10];
  const float* Wu2  = (const float*)d_in[11];
  const float* Wd3  = (const float*)d_in[12];
  const float* Wu3  = (const float*)d_in[13];
  float* out = (float*)d_out;
  char* ws = (char*)d_ws;
  // ws layout (total 38,486,080 B):
  unsigned short* Ax  = (unsigned short*)ws;                 // [16384][1088] bf16 = 35,651,584
  unsigned short* Bx  = (unsigned short*)(ws + 35651584);    // [1024][1088] bf16 =  2,228,224
  unsigned short* B1L = (unsigned short*)(ws + 37879808);    // [16][288][64] bf16 =   589,824
  float* v4           = (float*)(ws + 38469632);             // [4][1024] f32     =     16,384
  float* c4           = (float*)(ws + 38486016);             // [4] f32           =         64

  prep3<<<1024, 256, 0, stream>>>(W, Wp, sim, bp, Wd0, Wd1, Wd2, Wd3,
                                  Wu0, Wu1, Wu2, Wu3, Bx, B1L, Ax, v4, c4);
  gemm4f<<<256, 256, 0, stream>>>(x, v4, Ax, B1L, c4, bp, temp);
  main_gemm8<<<256, 512, 0, stream>>>(Ax, Bx, out);
}

// Round 19
// 96.735 us; speedup vs baseline: 1.0040x; 1.0040x over previous
//
#include <hip/hip_runtime.h>

#define TOK 16384
#define DD 1024
#define OO 1024
#define KE 1088     // 1024 + 16 lora cols + 48 zero pad (17 K-tiles of 64)
#define NT 17       // K-tiles in main GEMM
#define NB1 288     // B1 rows: 256 proj + 15 down + 17 zero pad
#define CLAMPV 4.605170185988091f

typedef __attribute__((ext_vector_type(8))) short short8;
typedef __attribute__((ext_vector_type(4))) float f32x4;
typedef __attribute__((ext_vector_type(2))) unsigned int uint2e;
typedef __attribute__((ext_vector_type(4))) unsigned int uint4e;

__device__ __forceinline__ unsigned short f2bf(float f) {
  unsigned int u = __float_as_uint(f);
  return (unsigned short)((u + 0x7FFFu + ((u >> 16) & 1u)) >> 16);
}

__device__ __forceinline__ void gload16(const unsigned short* g, unsigned short* l) {
  __builtin_amdgcn_global_load_lds(
      (const __attribute__((address_space(1))) void*)g,
      (__attribute__((address_space(3))) void*)l, 16, 0, 0);
}

__device__ __forceinline__ float down_val(int j, int d,
    const float* __restrict__ Wd0, const float* __restrict__ Wd1,
    const float* __restrict__ Wd2, const float* __restrict__ Wd3) {
  if (j == 0) return Wd0[d];
  if (j < 3) return Wd1[(j - 1) * DD + d];
  if (j < 7) return Wd2[(j - 3) * DD + d];
  if (j < 15) return Wd3[(j - 7) * DD + d];
  return 0.f;
}

// ---------------- kernel 0: prep (Bx bf16, B1L swizzle-blocked bf16, Ax pad, v4, c4) ----------------
// B1L layout: [16 K-tiles][288 rows][64 k] with k pre-XOR-swizzled: element (r, kt*64+k)
// stored at kk = k ^ ((r&7)<<3). Linear global_load_lds then yields T2-swizzled LDS.
__global__ __launch_bounds__(256) void prep3(
    const float* __restrict__ W, const float* __restrict__ Wp,
    const float* __restrict__ sim, const float* __restrict__ bp,
    const float* __restrict__ Wd0, const float* __restrict__ Wd1,
    const float* __restrict__ Wd2, const float* __restrict__ Wd3,
    const float* __restrict__ Wu0, const float* __restrict__ Wu1,
    const float* __restrict__ Wu2, const float* __restrict__ Wu3,
    unsigned short* __restrict__ Bx, unsigned short* __restrict__ B1,
    unsigned short* __restrict__ Ax, float* __restrict__ v4,
    float* __restrict__ c4) {
  __shared__ float simn_l[256][4];
  __shared__ float part[4][4];
  const int tid = threadIdx.x;
  if (blockIdx.x < 4) {
    float4 sv = *(const float4*)&sim[tid * 4];
    float v[4] = {sv.x * sv.x, sv.y * sv.y, sv.z * sv.z, sv.w * sv.w};
#pragma unroll
    for (int off = 1; off < 64; off <<= 1) {
#pragma unroll
      for (int e = 0; e < 4; ++e) v[e] += __shfl_xor(v[e], off, 64);
    }
    int wv = tid >> 6, ln = tid & 63;
    if (ln == 0) { part[wv][0] = v[0]; part[wv][1] = v[1]; part[wv][2] = v[2]; part[wv][3] = v[3]; }
    __syncthreads();
    float n0 = fmaxf(sqrtf(part[0][0] + part[1][0] + part[2][0] + part[3][0]), 1e-12f);
    float n1 = fmaxf(sqrtf(part[0][1] + part[1][1] + part[2][1] + part[3][1]), 1e-12f);
    float n2 = fmaxf(sqrtf(part[0][2] + part[1][2] + part[2][2] + part[3][2]), 1e-12f);
    float n3 = fmaxf(sqrtf(part[0][3] + part[1][3] + part[2][3] + part[3][3]), 1e-12f);
    simn_l[tid][0] = sv.x / n0; simn_l[tid][1] = sv.y / n1;
    simn_l[tid][2] = sv.z / n2; simn_l[tid][3] = sv.w / n3;
    __syncthreads();
    int d = blockIdx.x * 256 + tid;
    float a0 = 0.f, a1 = 0.f, a2 = 0.f, a3 = 0.f;
    for (int j = 0; j < 256; ++j) {
      float w = Wp[j * DD + d];
      a0 = __builtin_fmaf(w, simn_l[j][0], a0);
      a1 = __builtin_fmaf(w, simn_l[j][1], a1);
      a2 = __builtin_fmaf(w, simn_l[j][2], a2);
      a3 = __builtin_fmaf(w, simn_l[j][3], a3);
    }
    v4[d] = a0; v4[1024 + d] = a1; v4[2048 + d] = a2; v4[3072 + d] = a3;
    if (blockIdx.x == 0) {
      float bpv = bp[tid];
      float pc[4] = {simn_l[tid][0] * bpv, simn_l[tid][1] * bpv,
                     simn_l[tid][2] * bpv, simn_l[tid][3] * bpv};
#pragma unroll
      for (int off = 1; off < 64; off <<= 1) {
#pragma unroll
        for (int e = 0; e < 4; ++e) pc[e] += __shfl_xor(pc[e], off, 64);
      }
      __syncthreads();
      if (ln == 0) { part[wv][0] = pc[0]; part[wv][1] = pc[1]; part[wv][2] = pc[2]; part[wv][3] = pc[3]; }
      __syncthreads();
      if (tid == 0) {
#pragma unroll
        for (int e = 0; e < 4; ++e)
          c4[e] = part[0][e] + part[1][e] + part[2][e] + part[3][e];
      }
    }
  }
  const int nB1 = 16 * NB1 * 64;    // 294912 (swizzle-blocked)
  const int nWb = OO * KE;          // 1114112
  const int nXpad = TOK * 48;       // 786432 (cols 1040..1087)
  const int total = nB1 + nWb + nXpad;
  for (int i = blockIdx.x * 256 + tid; i < total; i += gridDim.x * 256) {
    if (i < nB1) {
      int kt = i / (NB1 * 64);
      int rem = i - kt * (NB1 * 64);
      int r = rem >> 6, kk = rem & 63;
      int k = kt * 64 + (kk ^ ((r & 7) << 3));
      float v = 0.f;
      if (r < 256) v = Wp[r * DD + k];
      else if (r < 271) v = down_val(r - 256, k, Wd0, Wd1, Wd2, Wd3);
      B1[i] = f2bf(v);
    } else if (i < nB1 + nWb) {
      int j = i - nB1;
      int o = j / KE, c = j - o * KE;
      float v = 0.f;
      if (c < 1024) v = W[o * DD + c];
      else if (c == 1024) v = Wu0[o];
      else if (c < 1027) v = Wu1[o * 2 + (c - 1025)];
      else if (c < 1031) v = Wu2[o * 4 + (c - 1027)];
      else if (c < 1039) v = Wu3[o * 8 + (c - 1031)];
      Bx[j] = f2bf(v);
    } else {
      int j = i - nB1 - nWb;
      int row = j / 48, c = j - row * 48;
      Ax[row * KE + 1040 + c] = 0;
    }
  }
}

// ---------------- kernel 1: gemm2f — BK=64, 16 iterations, T2-swizzled LDS ----------------
// 32 rows/block, 256 thr (4 waves 2m x 2n), grid 512 -> 2 blocks/CU. LDS exactly 80 KB.
// Ax stores are nontemporal (contiguous 64B stream; skip write-allocate/RFO).
__global__ __launch_bounds__(256, 2) void gemm2f(
    const float* __restrict__ x, const float* __restrict__ v4,
    unsigned short* __restrict__ Ax, const unsigned short* __restrict__ B1L,
    const float* __restrict__ c4, const float* __restrict__ bp,
    const float* __restrict__ temp) {
  __shared__ __align__(16) unsigned short as1[2][32 * 64];   //  8 KB
  __shared__ __align__(16) unsigned short bs1[2][NB1 * 64];  // 72 KB
  const int tid = threadIdx.x;
  const int lane = tid & 63, wv = tid >> 6;    // 4 waves
  const int wm = wv >> 1, wn = wv & 1;         // 2m x 2n (wn: 144 cols each)
  const int r0 = blockIdx.x * 32;
  const int ro = lane & 15;
  const int rswz = (ro & 7) << 3;              // read-side k-swizzle (ushort units)
  const int xr = tid >> 3;                     // x staging: row 0..31
  const int xc = (tid & 7) * 4;                // x staging: col quad within 32-col half
  const int aswz = (xr & 7) << 3;              // A write-side swizzle
  const float* xgp = &x[(r0 + xr) * DD + xc];
  unsigned short* axp = &Ax[(r0 + xr) * KE + xc];
  f32x4 acc[9] = {};
  float dotp[4] = {};

// 36 chunks of 8 rows x 64 k (1 KB); 36/4 waves = 9 gloads/thread, wave-uniform dest
#define STB1(KT, BUF)                                                         \
  for (int c = wv; c < 36; c += 4)                                            \
    gload16(&B1L[(KT) * (NB1 * 64) + c * 512 + lane * 8], &bs1[BUF][c * 512]);

#define XSTG(KT, BUF)                                                         \
  _Pragma("unroll")                                                           \
  for (int h = 0; h < 2; ++h) {                                               \
    float4 xv = *(const float4*)(xgp + (KT) * 64 + h * 32);                   \
    float4 va = *(const float4*)&v4[(KT) * 64 + h * 32 + xc];                 \
    float4 vb = *(const float4*)&v4[1024 + (KT) * 64 + h * 32 + xc];          \
    float4 vc = *(const float4*)&v4[2048 + (KT) * 64 + h * 32 + xc];          \
    float4 vd = *(const float4*)&v4[3072 + (KT) * 64 + h * 32 + xc];          \
    dotp[0] = __builtin_fmaf(xv.x, va.x, __builtin_fmaf(xv.y, va.y,           \
              __builtin_fmaf(xv.z, va.z, __builtin_fmaf(xv.w, va.w, dotp[0])))); \
    dotp[1] = __builtin_fmaf(xv.x, vb.x, __builtin_fmaf(xv.y, vb.y,           \
              __builtin_fmaf(xv.z, vb.z, __builtin_fmaf(xv.w, vb.w, dotp[1])))); \
    dotp[2] = __builtin_fmaf(xv.x, vc.x, __builtin_fmaf(xv.y, vc.y,           \
              __builtin_fmaf(xv.z, vc.z, __builtin_fmaf(xv.w, vc.w, dotp[2])))); \
    dotp[3] = __builtin_fmaf(xv.x, vd.x, __builtin_fmaf(xv.y, vd.y,           \
              __builtin_fmaf(xv.z, vd.z, __builtin_fmaf(xv.w, vd.w, dotp[3])))); \
    union { unsigned short s[4]; uint2e q; } pk;                              \
    pk.s[0] = f2bf(xv.x); pk.s[1] = f2bf(xv.y);                               \
    pk.s[2] = f2bf(xv.z); pk.s[3] = f2bf(xv.w);                               \
    __builtin_nontemporal_store(pk.q,                                         \
        reinterpret_cast<uint2e*>(axp + (KT) * 64 + h * 32));                 \
    *reinterpret_cast<uint2e*>(                                               \
        &as1[BUF][xr * 64 + (((h << 5) + xc) ^ aswz)]) = pk.q;                \
  }

#define MM(BUF)                                                               \
  _Pragma("unroll")                                                           \
  for (int kh = 0; kh < 2; ++kh) {                                            \
    const int kb = ((kh << 5) + ((lane >> 4) << 3)) ^ rswz;                   \
    short8 af = *reinterpret_cast<const short8*>(                             \
        &as1[BUF][(wm * 16 + ro) * 64 + kb]);                                 \
    _Pragma("unroll")                                                         \
    for (int n = 0; n < 9; ++n) {                                             \
      short8 bf = *reinterpret_cast<const short8*>(                           \
          &bs1[BUF][(wn * 144 + n * 16 + ro) * 64 + kb]);                     \
      acc[n] = __builtin_amdgcn_mfma_f32_16x16x32_bf16(af, bf, acc[n], 0, 0, 0); \
    }                                                                         \
  }

  // ---- prologue ----
  STB1(0, 0)
  XSTG(0, 0)
  __syncthreads();
  int cur = 0;
  for (int u = 0; u < 16; ++u) {
    if (u < 15) {
      STB1(u + 1, cur ^ 1)
      XSTG(u + 1, cur ^ 1)
    }
    MM(cur)
    if (u < 15) {
      __syncthreads();
      cur ^= 1;
    }
  }
  __syncthreads();

  // ---- epilogue scratch overlaid on bs1[0] (last MM read bs1[1]) ----
  float* eps = (float*)&bs1[0][0];
  float* ssq_s = eps;             // [2][32]
  float* xdown_s = eps + 64;      // [32][16]
  float* dots_s = eps + 576;      // [32][4]

  // fp32 dots: reduce over the 8 lanes sharing a row (lane bits 0..2)
#pragma unroll
  for (int off = 1; off < 8; off <<= 1) {
#pragma unroll
    for (int e = 0; e < 4; ++e) dotp[e] += __shfl_xor(dotp[e], off, 64);
  }
  if ((lane & 7) == 0) {
    dots_s[xr * 4 + 0] = dotp[0]; dots_s[xr * 4 + 1] = dotp[1];
    dots_s[xr * 4 + 2] = dotp[2]; dots_s[xr * 4 + 3] = dotp[3];
  }

  // per-thread ssq over proj cols (col < 256), bias added
  float ssqp[4] = {};
#pragma unroll
  for (int n = 0; n < 9; ++n) {
    int col = wn * 144 + n * 16 + ro;
    if (col < 256) {
      float b = bp[col];
#pragma unroll
      for (int r = 0; r < 4; ++r) {
        float a = acc[n][r] + b;
        ssqp[r] = __builtin_fmaf(a, a, ssqp[r]);
      }
    }
  }
#pragma unroll
  for (int off = 1; off < 16; off <<= 1) {
#pragma unroll
    for (int r = 0; r < 4; ++r) ssqp[r] += __shfl_xor(ssqp[r], off, 64);
  }
  if (ro == 0) {
#pragma unroll
    for (int r = 0; r < 4; ++r)
      ssq_s[wn * 32 + wm * 16 + (lane >> 4) * 4 + r] = ssqp[r];
  }
  // xdown cols 256..270: wn=1, frag n=7, ro<15
  if (wn == 1 && ro < 15) {
#pragma unroll
    for (int r = 0; r < 4; ++r)
      xdown_s[(wm * 16 + (lane >> 4) * 4 + r) * 16 + ro] = acc[7][r];
  }
  __syncthreads();

  if (tid < 32) {
    const int row = tid, t = r0 + row;
    float ssqT = ssq_s[row] + ssq_s[32 + row];
    float4 cc = *reinterpret_cast<const float4*>(c4);
    float scale = expf(fminf(temp[0], CLAMPV));
    float inv = scale / fmaxf(sqrtf(ssqT), 1e-12f);
    float l[4];
    l[0] = (dots_s[row * 4 + 0] + cc.x) * inv; l[1] = (dots_s[row * 4 + 1] + cc.y) * inv;
    l[2] = (dots_s[row * 4 + 2] + cc.z) * inv; l[3] = (dots_s[row * 4 + 3] + cc.w) * inv;
    int be = 0; float m = l[0];
    if (l[1] > m) { m = l[1]; be = 1; }
    if (l[2] > m) { m = l[2]; be = 2; }
    if (l[3] > m) { m = l[3]; be = 3; }
    float den = expf(l[0] - m) + expf(l[1] - m) + expf(l[2] - m) + expf(l[3] - m);
    float g = 1.0f / den;
    int off = (1 << be) - 1;   // {0,1,3,7}
    int rr = 1 << be;          // {1,2,4,8}
    union { unsigned short s[16]; uint4e v[2]; } o;
#pragma unroll
    for (int j = 0; j < 16; ++j) {
      float dv = xdown_s[row * 16 + (j & 15)];
      float v = (j >= off && j < off + rr) ? g * dv : 0.f;
      o.s[j] = f2bf(v);
    }
    uint4e* dst = reinterpret_cast<uint4e*>(&Ax[t * KE + 1024]);
    __builtin_nontemporal_store(o.v[0], dst);
    __builtin_nontemporal_store(o.v[1], dst + 1);
  }
#undef STB1
#undef XSTG
#undef MM
}

// ---------------- kernel 2: main_gemm8 — 256x256 8-phase bf16 MFMA GEMM ----------------
// Unchanged schedule; C write via PLAIN stores (nt caused partial-line write
// amplification: 65.5 -> 89 MB WRITE_SIZE, +17 us — measured r16, reverted).
__global__ __launch_bounds__(512, 2) void main_gemm8(
    const unsigned short* __restrict__ A, const unsigned short* __restrict__ Bm,
    float* __restrict__ C) {
  __shared__ __align__(16) unsigned short lbuf[2][32768];
  const int tid = threadIdx.x;
  const int lane = tid & 63, wv = tid >> 6;
  const int wm = wv >> 2, wn = wv & 3;
  const int dd = blockIdx.x;
  const int tt = (dd & 7) * 32 + (dd >> 3);
  const int bx = tt & 3, by = tt >> 2;
  const int r0 = by * 256, c0 = bx * 256;
  const int ro = lane & 15, ko = (lane >> 4) * 8;
  const int rowb = ro * 128;
  const int swz = (ro & 7) << 4;
  const int lk0 = (ko * 2) ^ swz;
  const int lk1 = (64 + ko * 2) ^ swz;
  const int ll = (lane * 16) ^ ((lane >> 3) << 4);
  const int sro = ll >> 7;
  const int sk = (ll & 127) >> 1;
  f32x4 acc[8][4] = {};
  short8 Af[4][2], B0[2][2], B1r[2][2];

#define STG(MTX, GRB, HBU, BUF, U2)                                           \
  do {                                                                        \
    gload16(&MTX[((GRB) + (0 * 8 + wv) * 8 + sro) * KE + (U2) * 64 + sk],     \
            &lbuf[BUF][(HBU) + (0 * 8 + wv) * 512]);                          \
    gload16(&MTX[((GRB) + (1 * 8 + wv) * 8 + sro) * KE + (U2) * 64 + sk],     \
            &lbuf[BUF][(HBU) + (1 * 8 + wv) * 512]);                          \
  } while (0)

#define LDA(FI, QM, LK) (*reinterpret_cast<const short8*>(                    \
    (const char*)Ab + wm * 16384 + (QM) * 8192 + (FI) * 2048 + rowb + (LK)))
#define LDB(FN, QN, LK) (*reinterpret_cast<const short8*>(                    \
    (const char*)Bb + wn * 8192 + (QN) * 4096 + (FN) * 2048 + rowb + (LK)))

#define MMQ(QM, QN, BF)                                                       \
  do {                                                                        \
    _Pragma("unroll")                                                         \
    for (int fi = 0; fi < 4; ++fi) {                                          \
      _Pragma("unroll")                                                       \
      for (int fn = 0; fn < 2; ++fn) {                                        \
        acc[(QM)*4+fi][(QN)*2+fn] = __builtin_amdgcn_mfma_f32_16x16x32_bf16(  \
            Af[fi][0], BF[fn][0], acc[(QM)*4+fi][(QN)*2+fn], 0, 0, 0);        \
        acc[(QM)*4+fi][(QN)*2+fn] = __builtin_amdgcn_mfma_f32_16x16x32_bf16(  \
            Af[fi][1], BF[fn][1], acc[(QM)*4+fi][(QN)*2+fn], 0, 0, 0);        \
      }                                                                       \
    }                                                                         \
  } while (0)

  STG(Bm, c0,       16384, 0, 0);
  STG(A,  r0,       0,     0, 0);
  STG(Bm, c0 + 128, 24576, 0, 0);
  STG(A,  r0 + 128, 8192,  0, 0);
  STG(Bm, c0,       16384, 1, 1);
  STG(A,  r0,       0,     1, 1);
  asm volatile("s_waitcnt vmcnt(4)" ::: "memory");
  __builtin_amdgcn_s_barrier();

  for (int u = 0; u < NT; ++u) {
    const int db = u & 1;
    const unsigned short* Ab = &lbuf[db][0];
    const unsigned short* Bb = &lbuf[db][16384];
#pragma unroll
    for (int fi = 0; fi < 4; ++fi) { Af[fi][0] = LDA(fi, 0, lk0); Af[fi][1] = LDA(fi, 0, lk1); }
#pragma unroll
    for (int fn = 0; fn < 2; ++fn) { B0[fn][0] = LDB(fn, 0, lk0); B0[fn][1] = LDB(fn, 0, lk1); }
    if (u + 1 < NT) STG(Bm, c0 + 128, 24576, (u + 1) & 1, u + 1);
    __builtin_amdgcn_s_barrier();
    __builtin_amdgcn_s_setprio(1);
    MMQ(0, 0, B0);
    __builtin_amdgcn_s_setprio(0);
    __builtin_amdgcn_s_barrier();
#pragma unroll
    for (int fn = 0; fn < 2; ++fn) { B1r[fn][0] = LDB(fn, 1, lk0); B1r[fn][1] = LDB(fn, 1, lk1); }
    if (u + 1 < NT) STG(A, r0 + 128, 8192, (u + 1) & 1, u + 1);
    __builtin_amdgcn_s_barrier();
    __builtin_amdgcn_s_setprio(1);
    MMQ(0, 1, B1r);
    __builtin_amdgcn_s_setprio(0);
    __builtin_amdgcn_s_barrier();
#pragma unroll
    for (int fi = 0; fi < 4; ++fi) { Af[fi][0] = LDA(fi, 1, lk0); Af[fi][1] = LDA(fi, 1, lk1); }
    if (u + 2 < NT) STG(Bm, c0, 16384, db, u + 2);
    __builtin_amdgcn_s_barrier();
    __builtin_amdgcn_s_setprio(1);
    MMQ(1, 1, B1r);
    __builtin_amdgcn_s_setprio(0);
    __builtin_amdgcn_s_barrier();
    if (u + 2 < NT) STG(A, r0, 0, db, u + 2);
    __builtin_amdgcn_s_barrier();
    __builtin_amdgcn_s_setprio(1);
    MMQ(1, 0, B0);
    __builtin_amdgcn_s_setprio(0);
    if (u + 2 < NT) {
      asm volatile("s_waitcnt vmcnt(4)" ::: "memory");
    } else if (u == NT - 2) {
      asm volatile("s_waitcnt vmcnt(0)" ::: "memory");
    }
    __builtin_amdgcn_s_barrier();
  }

#pragma unroll
  for (int m = 0; m < 8; ++m) {
    int rr = r0 + wm * 128 + m * 16 + (lane >> 4) * 4;
#pragma unroll
    for (int n = 0; n < 4; ++n) {
      int cc = c0 + wn * 64 + n * 16 + ro;
#pragma unroll
      for (int v = 0; v < 4; ++v)
        C[(rr + v) * OO + cc] = acc[m][n][v];
    }
  }
#undef STG
#undef LDA
#undef LDB
#undef MMQ
}

extern "C" void kernel_launch(void* const* d_in, const int* in_sizes, int n_in,
                              void* d_out, int out_size, void* d_ws, size_t ws_size,
                              hipStream_t stream) {
  const float* x    = (const float*)d_in[0];
  const float* W    = (const float*)d_in[1];
  const float* Wp   = (const float*)d_in[2];
  const float* bp   = (const float*)d_in[3];
  const float* sim  = (const float*)d_in[4];
  const float* temp = (const float*)d_in[5];
  const float* Wd0  = (const float*)d_in[6];
  const float* Wu0  = (const float*)d_in[7];
  const float* Wd1  = (const float*)d_in[8];
  const float* Wu1  = (const float*)d_in[9];
  const float* Wd2  = (const float*)d_in[10];
  const float* Wu2  = (const float*)d_in[11];
  const float* Wd3  = (const float*)d_in[12];
  const float* Wu3  = (const float*)d_in[13];
  float* out = (float*)d_out;
  char* ws = (char*)d_ws;
  // ws layout (total 38,486,080 B):
  unsigned short* Ax  = (unsigned short*)ws;                 // [16384][1088] bf16 = 35,651,584
  unsigned short* Bx  = (unsigned short*)(ws + 35651584);    // [1024][1088] bf16 =  2,228,224
  unsigned short* B1L = (unsigned short*)(ws + 37879808);    // [16][288][64] bf16 =   589,824
  float* v4           = (float*)(ws + 38469632);             // [4][1024] f32     =     16,384
  float* c4           = (float*)(ws + 38486016);             // [4] f32           =         64

  prep3<<<1024, 256, 0, stream>>>(W, Wp, sim, bp, Wd0, Wd1, Wd2, Wd3,
                                  Wu0, Wu1, Wu2, Wu3, Bx, B1L, Ax, v4, c4);
  gemm2f<<<512, 256, 0, stream>>>(x, v4, Ax, B1L, c4, bp, temp);
  main_gemm8<<<256, 512, 0, stream>>>(Ax, Bx, out);
}